// Round 7
// baseline (176.889 us; speedup 1.0000x reference)
//
#include <hip/hip_runtime.h>
#include <math.h>

namespace {

constexpr int Bn = 64, Cn = 128, Tn = 512, Hn = 256;
constexpr int MR = 128;          // t-rows per block
constexpr int TB = Tn / MR;      // 4 -> grid 256 (1 block/CU)
constexpr float LN_EPS = 1e-5f;

constexpr int NQ = 54;           // chunks: 0..15 L1 spline, 16..17 L1 silu,
                                 //         18..49 L2 spline, 50..53 L2 silu
constexpr int RB = 144;          // tile row stride bytes (72 shorts: 64k + pad)
constexpr int L1B = 36864;       // L1 chunk bytes: 256 rows x 144
constexpr int L2B = 18432;       // L2 chunk bytes: 128 rows x 144
constexpr int W2OFF = 18 * L1B;  // byte offset of L2 chunks in packed W

typedef __attribute__((ext_vector_type(8))) short short8;
typedef __attribute__((ext_vector_type(16))) float f32x16;

__device__ __forceinline__ unsigned short f2bf(float f) {
  unsigned int u = __builtin_bit_cast(unsigned int, f);
  u = (u + 0x7fffu + ((u >> 16) & 1u)) >> 16;
  return (unsigned short)u;
}
__device__ __forceinline__ float bf2f(unsigned short u) {
  unsigned int v = (unsigned int)u << 16;
  return __builtin_bit_cast(float, v);
}
__device__ __forceinline__ float siluf(float z) {
  return z * __builtin_amdgcn_rcpf(1.0f + __expf(-z));
}

// Closed-form uniform cubic B-spline on grid g[j]=0.4*(j-3)-1; returns the
// 8 basis values (j=0..7) packed bf16. Matches the reference recursion.
__device__ __forceinline__ short8 spline_pack(float z) {
  const float p = z * 2.5f + 5.5f;
  const float fi = floorf(p);
  const int ib = (int)fi - 3;  // first nonzero j
  const float u = p - fi;
  const float u2 = u * u, u3 = u2 * u, tt = 1.0f - u;
  const float w0 = tt * tt * tt * (1.0f / 6.0f);
  const float w1 = (3.0f * u3 - 6.0f * u2 + 4.0f) * (1.0f / 6.0f);
  const float w2 = (-3.0f * u3 + 3.0f * u2 + 3.0f * u + 1.0f) * (1.0f / 6.0f);
  const float w3 = u3 * (1.0f / 6.0f);
  short8 r;
#pragma unroll
  for (int j = 0; j < 8; ++j) {
    const int d = j - ib;
    const float v =
        (d == 0) ? w0 : (d == 1) ? w1 : (d == 2) ? w2 : (d == 3) ? w3 : 0.0f;
    r[j] = (short)f2bf(v);
  }
  return r;
}

__device__ __forceinline__ size_t wsrc_byte(int q) {
  return (q < 18) ? (size_t)q * L1B : (size_t)W2OFF + (size_t)(q - 18) * L2B;
}

}  // namespace

#define BAR_LGKM()                                         \
  do {                                                     \
    asm volatile("s_waitcnt lgkmcnt(0)" ::: "memory");     \
    __builtin_amdgcn_s_barrier();                          \
    asm volatile("" ::: "memory");                         \
  } while (0)
#define BAR_FULL()                                                  \
  do {                                                              \
    asm volatile("s_waitcnt vmcnt(0) lgkmcnt(0)" ::: "memory");     \
    __builtin_amdgcn_s_barrier();                                   \
    asm volatile("" ::: "memory");                                  \
  } while (0)

// ---------------------------------------------------------------------------
// Prep: pack weights into pre-swizzled chunk tiles (so a LINEAR global->LDS
// copy yields the swizzled LDS image; readers XOR byte bits 4-5 with
// (row>>3)&3).  kloc = feat_local*8 + j (spline chunks) or c_local (silu).
// Also: per-batch LN partial sums; bf16 transpose of ln_w/ln_b to [c][t].
// ---------------------------------------------------------------------------
__global__ __launch_bounds__(256) void kan_prep(
    const float* __restrict__ U, const float* __restrict__ ln_w,
    const float* __restrict__ ln_b, const float* __restrict__ bw1,
    const float* __restrict__ sw1, const float* __restrict__ ss1,
    const float* __restrict__ bw2, const float* __restrict__ sw2,
    const float* __restrict__ ss2, unsigned short* __restrict__ Wp,
    unsigned short* __restrict__ lnwT, unsigned short* __restrict__ lnbT,
    float* __restrict__ stats) {
  __shared__ float red[2][4];
  const int blk = blockIdx.x;
  if (blk < 128) {  // ---- W1 pack: idx = h*128 + c ----
    const int idx = blk * 256 + threadIdx.x;
    const int h = idx >> 7, c = idx & 127;
    const float sc = ss1[idx];
    const float* spw = sw1 + (size_t)idx * 8;
    const int swz = ((h >> 3) & 3) << 4;
    short8 v;
#pragma unroll
    for (int j = 0; j < 8; ++j) v[j] = (short)f2bf(spw[j] * sc);
    const int sb = (h * RB + (c & 7) * 16) ^ swz;
    *(short8*)((char*)Wp + (size_t)(c >> 3) * L1B + sb) = v;
    const int ub = (h * RB + (c & 63) * 2) ^ swz;
    *(unsigned short*)((char*)Wp + (size_t)(16 + (c >> 6)) * L1B + ub) =
        f2bf(bw1[idx]);
  } else if (blk < 256) {  // ---- W2 pack: idx = c*256 + h ----
    const int idx = (blk - 128) * 256 + threadIdx.x;
    const int c = idx >> 8, h = idx & 255;
    const float sc = ss2[idx];
    const float* spw = sw2 + (size_t)idx * 8;
    const int swz = ((c >> 3) & 3) << 4;
    short8 v;
#pragma unroll
    for (int j = 0; j < 8; ++j) v[j] = (short)f2bf(spw[j] * sc);
    const int sb = (c * RB + (h & 7) * 16) ^ swz;
    *(short8*)((char*)Wp + W2OFF + (size_t)(h >> 3) * L2B + sb) = v;
    const int ub = (c * RB + (h & 63) * 2) ^ swz;
    *(unsigned short*)((char*)Wp + W2OFF + (size_t)(32 + (h >> 6)) * L2B + ub) =
        f2bf(bw2[idx]);
  } else if (blk < 512) {  // ---- LN stats partials ----
    const int sblk = blk - 256;
    const int b = sblk >> 2, q = sblk & 3;
    const float4* p =
        (const float4*)(U + (size_t)b * (Cn * Tn) + q * (Cn * Tn / 4));
    float s = 0.f, s2 = 0.f;
#pragma unroll 4
    for (int i = threadIdx.x; i < (Cn * Tn / 4) / 4; i += 256) {
      const float4 v4 = p[i];
      s += v4.x + v4.y + v4.z + v4.w;
      s2 += v4.x * v4.x + v4.y * v4.y + v4.z * v4.z + v4.w * v4.w;
    }
#pragma unroll
    for (int off = 32; off > 0; off >>= 1) {
      s += __shfl_down(s, off);
      s2 += __shfl_down(s2, off);
    }
    if ((threadIdx.x & 63) == 0) {
      red[0][threadIdx.x >> 6] = s;
      red[1][threadIdx.x >> 6] = s2;
    }
    __syncthreads();
    if (threadIdx.x == 0) {
      stats[b * 8 + q * 2 + 0] = red[0][0] + red[0][1] + red[0][2] + red[0][3];
      stats[b * 8 + q * 2 + 1] = red[1][0] + red[1][1] + red[1][2] + red[1][3];
    }
  } else {  // ---- ln_w/ln_b transpose to bf16 [c][t] ----
    const int bb = blk - 512;  // 0..127
    const float* src = (bb < 64) ? ln_w : ln_b;
    unsigned short* dst = (bb < 64) ? lnwT : lnbT;
    const int base = (bb & 63) * 1024;
#pragma unroll
    for (int e2 = 0; e2 < 4; ++e2) {
      const int i = base + (int)threadIdx.x + e2 * 256;  // c*512 + t
      dst[i] = f2bf(src[(i & 511) * Cn + (i >> 9)]);
    }
  }
}

// ---------------------------------------------------------------------------
// Fused LN -> KAN1 -> KAN2 -> residual. 256 blocks x 512 threads (8 waves),
// 1 block/CU, LDS 158 KB. Weights DMA'd chunk-by-chunk (double-buffered);
// acts computed into a single LDS buffer between barriers; counted-vmcnt
// discipline: DMA issued in phase A survives the raw barrier, drained at
// phase-B end.
// ---------------------------------------------------------------------------
__global__ __launch_bounds__(512, 2) void kan_fused(
    const float* __restrict__ U, const unsigned short* __restrict__ lnwT,
    const unsigned short* __restrict__ lnbT,
    const unsigned short* __restrict__ Wp, const float* __restrict__ stats,
    float* __restrict__ out) {
  __shared__ __align__(16) unsigned short s_w[2][L1B / 2];  // 73,728 B
  __shared__ __align__(16) unsigned short s_a[MR * 72];     // 18,432 B
  __shared__ __align__(16) unsigned short s_h1[MR * 258];   // 66,048 B

  const int tid = threadIdx.x;
  const int b = blockIdx.x >> 2;
  const int t0 = (blockIdx.x & 3) * MR;

  const float* sp = stats + b * 8;
  const float ssum = sp[0] + sp[2] + sp[4] + sp[6];
  const float ssq = sp[1] + sp[3] + sp[5] + sp[7];
  const float inv_n = 1.0f / (float)(Cn * Tn);
  const float mean = ssum * inv_n;
  const float rstd = rsqrtf(ssq * inv_n - mean * mean + LN_EPS);

  const int w = tid >> 6, l = tid & 63;
  const int ln31 = l & 31, hl = l >> 5;
  const int mi = w >> 2, ni = w & 3;     // wave tile: rows mi*64, cols ni*64|32
  const int arow = tid & 127;            // act producer row
  const int afe = tid >> 7;              // act producer feat group 0..3
  const int aswz = ((arow >> 3) & 3) << 4;
  const int fswz = ((ln31 >> 3) & 3) << 4;

  f32x16 acc00 = {}, acc01 = {}, acc10 = {}, acc11 = {};  // layer 1
  f32x16 acc20 = {}, acc21 = {};                          // layer 2

  // ---- weight DMA: linear copy of pre-swizzled chunk ----
  auto stage = [&](int q, int buf) {
    const char* src = (const char*)Wp + wsrc_byte(q);
    char* dstb = (char*)&s_w[buf][0];
    const int nIss = (q < 18) ? 36 : 18;
    for (int i = w; i < nIss; i += 8) {
      const char* gp = src + i * 1024 + l * 16;
      char* lp = dstb + i * 1024;
      __builtin_amdgcn_global_load_lds(
          (const __attribute__((address_space(1))) unsigned int*)gp,
          (__attribute__((address_space(3))) unsigned int*)lp, 16, 0, 0);
    }
  };

  auto store8 = [&](int f, short8 v) {
    *(short8*)((char*)s_a + ((arow * RB + f * 16) ^ aswz)) = v;
  };

  auto mfma_l1 = [&](int buf) {
    const char* ab = (const char*)s_a;
    const char* bb = (const char*)&s_w[buf][0];
    const int ra0 = (mi * 64 + ln31) * RB, ra1 = ra0 + 32 * RB;
    const int rb0 = (ni * 64 + ln31) * RB, rb1 = rb0 + 32 * RB;
#pragma unroll
    for (int ks = 0; ks < 4; ++ks) {
      const int kb = ks * 32 + hl * 16;
      const short8 a0 = *(const short8*)(ab + ((ra0 + kb) ^ fswz));
      const short8 a1 = *(const short8*)(ab + ((ra1 + kb) ^ fswz));
      const short8 b0 = *(const short8*)(bb + ((rb0 + kb) ^ fswz));
      const short8 b1 = *(const short8*)(bb + ((rb1 + kb) ^ fswz));
      acc00 = __builtin_amdgcn_mfma_f32_32x32x16_bf16(a0, b0, acc00, 0, 0, 0);
      acc01 = __builtin_amdgcn_mfma_f32_32x32x16_bf16(a0, b1, acc01, 0, 0, 0);
      acc10 = __builtin_amdgcn_mfma_f32_32x32x16_bf16(a1, b0, acc10, 0, 0, 0);
      acc11 = __builtin_amdgcn_mfma_f32_32x32x16_bf16(a1, b1, acc11, 0, 0, 0);
    }
  };
  auto mfma_l2 = [&](int buf) {
    const char* ab = (const char*)s_a;
    const char* bb = (const char*)&s_w[buf][0];
    const int ra0 = (mi * 64 + ln31) * RB, ra1 = ra0 + 32 * RB;
    const int rb0 = (ni * 32 + ln31) * RB;
#pragma unroll
    for (int ks = 0; ks < 4; ++ks) {
      const int kb = ks * 32 + hl * 16;
      const short8 a0 = *(const short8*)(ab + ((ra0 + kb) ^ fswz));
      const short8 a1 = *(const short8*)(ab + ((ra1 + kb) ^ fswz));
      const short8 b0 = *(const short8*)(bb + ((rb0 + kb) ^ fswz));
      acc20 = __builtin_amdgcn_mfma_f32_32x32x16_bf16(a0, b0, acc20, 0, 0, 0);
      acc21 = __builtin_amdgcn_mfma_f32_32x32x16_bf16(a1, b0, acc21, 0, 0, 0);
    }
  };

  // =========================== prologue ===========================
  {
    const int t = t0 + arow;
    const int c0 = afe, c1 = afe + 4;
    const float zu0 = U[((size_t)b * Cn + c0) * Tn + t];
    const float zu1 = U[((size_t)b * Cn + c1) * Tn + t];
    const unsigned short w0 = lnwT[c0 * Tn + t], b0 = lnbT[c0 * Tn + t];
    const unsigned short w1 = lnwT[c1 * Tn + t], b1 = lnbT[c1 * Tn + t];
    stage(0, 0);
    const float z0 = (zu0 - mean) * rstd * bf2f(w0) + bf2f(b0);
    const float z1 = (zu1 - mean) * rstd * bf2f(w1) + bf2f(b1);
    store8(afe, spline_pack(z0));
    store8(afe + 4, spline_pack(z1));
  }
  BAR_FULL();

  // ==================== L1 spline chunks 0..15 ====================
  for (int q = 0; q < 16; ++q) {
    const int buf = q & 1;
    float zu0 = 0.f, zu1 = 0.f;
    unsigned short w0 = 0, w1 = 0, b0 = 0, b1 = 0;
    float pf0[8], pf1[8];
    unsigned short pu0[8], pu1[8], pv0[8], pv1[8];
    const bool nspl = q < 15;  // next chunk type
    {  // phase A: preload next-act inputs + issue next DMA + MFMA
      const int t = t0 + arow;
      if (nspl) {
        const int c0 = (q + 1) * 8 + afe, c1 = c0 + 4;
        zu0 = U[((size_t)b * Cn + c0) * Tn + t];
        zu1 = U[((size_t)b * Cn + c1) * Tn + t];
        w0 = lnwT[c0 * Tn + t]; b0 = lnbT[c0 * Tn + t];
        w1 = lnwT[c1 * Tn + t]; b1 = lnbT[c1 * Tn + t];
      } else {  // next is silu chunk 16 (channels 0..63)
#pragma unroll
        for (int j = 0; j < 8; ++j) {
          const int c0 = afe * 8 + j, c1 = (afe + 4) * 8 + j;
          pf0[j] = U[((size_t)b * Cn + c0) * Tn + t];
          pu0[j] = lnwT[c0 * Tn + t]; pv0[j] = lnbT[c0 * Tn + t];
          pf1[j] = U[((size_t)b * Cn + c1) * Tn + t];
          pu1[j] = lnwT[c1 * Tn + t]; pv1[j] = lnbT[c1 * Tn + t];
        }
      }
      stage(q + 1, buf ^ 1);
      mfma_l1(buf);
    }
    BAR_LGKM();
    {  // phase B: fire next act
      if (nspl) {
        const float z0 = (zu0 - mean) * rstd * bf2f(w0) + bf2f(b0);
        const float z1 = (zu1 - mean) * rstd * bf2f(w1) + bf2f(b1);
        store8(afe, spline_pack(z0));
        store8(afe + 4, spline_pack(z1));
      } else {
        short8 va, vb;
#pragma unroll
        for (int j = 0; j < 8; ++j) {
          va[j] = (short)f2bf(
              siluf((pf0[j] - mean) * rstd * bf2f(pu0[j]) + bf2f(pv0[j])));
          vb[j] = (short)f2bf(
              siluf((pf1[j] - mean) * rstd * bf2f(pu1[j]) + bf2f(pv1[j])));
        }
        store8(afe, va);
        store8(afe + 4, vb);
      }
    }
    BAR_FULL();
  }

  // ==================== L1 silu chunks 16..17 ====================
  {  // q = 16: preload+fire silu 17 (channels 64..127)
    float pf0[8], pf1[8];
    unsigned short pu0[8], pu1[8], pv0[8], pv1[8];
    const int t = t0 + arow;
#pragma unroll
    for (int j = 0; j < 8; ++j) {
      const int c0 = 64 + afe * 8 + j, c1 = 64 + (afe + 4) * 8 + j;
      pf0[j] = U[((size_t)b * Cn + c0) * Tn + t];
      pu0[j] = lnwT[c0 * Tn + t]; pv0[j] = lnbT[c0 * Tn + t];
      pf1[j] = U[((size_t)b * Cn + c1) * Tn + t];
      pu1[j] = lnwT[c1 * Tn + t]; pv1[j] = lnbT[c1 * Tn + t];
    }
    stage(17, 1);
    mfma_l1(0);
    BAR_LGKM();
    short8 va, vb;
#pragma unroll
    for (int j = 0; j < 8; ++j) {
      va[j] = (short)f2bf(
          siluf((pf0[j] - mean) * rstd * bf2f(pu0[j]) + bf2f(pv0[j])));
      vb[j] = (short)f2bf(
          siluf((pf1[j] - mean) * rstd * bf2f(pu1[j]) + bf2f(pv1[j])));
    }
    store8(afe, va);
    store8(afe + 4, vb);
    BAR_FULL();
  }
  {  // q = 17: MFMA; h1 epilogue; act2 for chunk 18
    stage(18, 0);
    mfma_l1(1);
    BAR_LGKM();
    // h1 -> LDS bf16 (C layout: col = lane&31, row = (r&3)+8*(r>>2)+4*hl)
#pragma unroll
    for (int r = 0; r < 16; ++r) {
      const int rr = 4 * hl + (r & 3) + 8 * (r >> 2);
      const int colb = ni * 64 + ln31;
      s_h1[(mi * 64 + rr) * 258 + colb] = f2bf(acc00[r]);
      s_h1[(mi * 64 + rr) * 258 + colb + 32] = f2bf(acc01[r]);
      s_h1[(mi * 64 + 32 + rr) * 258 + colb] = f2bf(acc10[r]);
      s_h1[(mi * 64 + 32 + rr) * 258 + colb + 32] = f2bf(acc11[r]);
    }
    BAR_LGKM();
    const float z0 = bf2f(s_h1[arow * 258 + afe]);
    const float z1 = bf2f(s_h1[arow * 258 + afe + 4]);
    store8(afe, spline_pack(z0));
    store8(afe + 4, spline_pack(z1));
    BAR_FULL();
  }

  // ==================== L2 spline chunks 18..49 ====================
  for (int q = 18; q < 50; ++q) {
    const int buf = q & 1;
    unsigned short h0 = 0, h1v = 0;
    unsigned short pu0[8], pu1[8];
    const bool nspl = q < 49;
    {
      if (nspl) {
        const int hb = (q - 17) * 8;
        h0 = s_h1[arow * 258 + hb + afe];
        h1v = s_h1[arow * 258 + hb + afe + 4];
      } else {  // next is silu chunk 50 (h 0..63)
#pragma unroll
        for (int j = 0; j < 8; ++j) {
          pu0[j] = s_h1[arow * 258 + afe * 8 + j];
          pu1[j] = s_h1[arow * 258 + (afe + 4) * 8 + j];
        }
      }
      stage(q + 1, buf ^ 1);
      mfma_l2(buf);
    }
    BAR_LGKM();
    {
      if (nspl) {
        store8(afe, spline_pack(bf2f(h0)));
        store8(afe + 4, spline_pack(bf2f(h1v)));
      } else {
        short8 va, vb;
#pragma unroll
        for (int j = 0; j < 8; ++j) {
          va[j] = (short)f2bf(siluf(bf2f(pu0[j])));
          vb[j] = (short)f2bf(siluf(bf2f(pu1[j])));
        }
        store8(afe, va);
        store8(afe + 4, vb);
      }
    }
    BAR_FULL();
  }

  // ==================== L2 silu chunks 50..53 ====================
  for (int q = 50; q < NQ; ++q) {
    const int buf = q & 1;
    unsigned short pu0[8], pu1[8];
    const bool more = q < NQ - 1;
    {
      if (more) {
        const int hb = (q - 49) * 64;
#pragma unroll
        for (int j = 0; j < 8; ++j) {
          pu0[j] = s_h1[arow * 258 + hb + afe * 8 + j];
          pu1[j] = s_h1[arow * 258 + hb + (afe + 4) * 8 + j];
        }
        stage(q + 1, buf ^ 1);
      }
      mfma_l2(buf);
    }
    if (more) {
      BAR_LGKM();
      short8 va, vb;
#pragma unroll
      for (int j = 0; j < 8; ++j) {
        va[j] = (short)f2bf(siluf(bf2f(pu0[j])));
        vb[j] = (short)f2bf(siluf(bf2f(pu1[j])));
      }
      store8(afe, va);
      store8(afe + 4, vb);
      BAR_FULL();
    }
  }

  // ==================== epilogue: residual + store ====================
  const int c = ni * 32 + ln31;
#pragma unroll
  for (int mi2 = 0; mi2 < 2; ++mi2) {
#pragma unroll
    for (int g = 0; g < 4; ++g) {
      const int trow = t0 + mi * 64 + mi2 * 32 + 8 * g + 4 * hl;
      const size_t base = ((size_t)b * Cn + c) * Tn + trow;
      const float4 uin = *(const float4*)(U + base);
      float4 o;
      const f32x16& a2 = mi2 ? acc21 : acc20;
      o.x = uin.x + a2[g * 4 + 0];
      o.y = uin.y + a2[g * 4 + 1];
      o.z = uin.z + a2[g * 4 + 2];
      o.w = uin.w + a2[g * 4 + 3];
      *(float4*)(out + base) = o;
    }
  }
}

extern "C" void kernel_launch(void* const* d_in, const int* in_sizes, int n_in,
                              void* d_out, int out_size, void* d_ws,
                              size_t ws_size, hipStream_t stream) {
  const float* U = (const float*)d_in[0];
  const float* ln_w = (const float*)d_in[1];
  const float* ln_b = (const float*)d_in[2];
  const float* bw1 = (const float*)d_in[3];
  const float* sw1 = (const float*)d_in[4];
  const float* ss1 = (const float*)d_in[5];
  const float* bw2 = (const float*)d_in[6];
  const float* sw2 = (const float*)d_in[7];
  const float* ss2 = (const float*)d_in[8];
  float* out = (float*)d_out;

  char* ws = (char*)d_ws;
  float* stats = (float*)ws;                            // 4 KB
  unsigned short* lnwT = (unsigned short*)(ws + 4096);  // 128 KB
  unsigned short* lnbT = lnwT + Cn * Tn;                // 128 KB
  unsigned short* Wp = lnbT + Cn * Tn;                  // 1,327,104 B packed W

  kan_prep<<<640, 256, 0, stream>>>(U, ln_w, ln_b, bw1, sw1, ss1, bw2, sw2,
                                    ss2, Wp, lnwT, lnbT, stats);
  kan_fused<<<Bn * TB, 512, 0, stream>>>(U, lnwT, lnbT, Wp, stats, out);
}